// Round 15
// baseline (233.073 us; speedup 1.0000x reference)
//
#include <hip/hip_runtime.h>
#include <hip/hip_fp16.h>

// CapsNet dynamic routing, B=256, P=2048, C=10, OUT=16, IN=8, 3 iters.
// R21: barrier-free waves. R18/R20 timing model => per-block fixed cost
// F ~ 23us (W-DMA + drain barrier + 80-scattered-load v-prologue) vs
// c ~ 1.6us/p of compute; residency pinned ~8 waves/CU in every config.
// So delete the block: NO LDS, NO __syncthreads, NO gl_lds. Each wave is
// independent, owns a (16b x 8p) tile. A-frag W[p][c][col*8] read DIRECTLY
// from global: lanes 0-15 span 256B, quads replicate -> one coalesced 256B
// L2-hot fetch per instr (W = 5.25MB fp16, read ~16x -> ~84MB L2, ~3us).
// v-prologue moved to k_vprep (2560 threads): squash(s) packed to
// vT[b][quad][10c][4o] fp16 -> k_cap loads it as FIVE contiguous 16B loads
// (was ~80 scattered float4 + serial squash chains).
// MODE2 v12 = squash(.1 s1)+squash(s2) computed in k_vprep<2> (lg stays
// deleted, R16 algebra). Counters disambiguate the residency question:
// occupancy rises => pin was block-structure; flat ~20% => scheduler-real.
// FETCH >> 20MB => VGPR spill (revert rule).
// Carried: MFMA map A=W[p][c][o=col][0..8) (original layout, 16B/lane),
// B=uT row (quad0 real, quads1-3 K-pad zeros), C/D lane(quad,col) =
// uh[o=quad*4+reg][b=col]; softmax 2 shfl_xor/c + all-10 in-lane;
// owner-unique coalesced part stores (NO atomics in k_cap); uT[p][b][8]
// fp16 (paired prep); k_red (160,8) 32-chunk atomicAdd into memset s.
// part layout now [ptile=256][b=256][160] fp32 = 42MB.
// Passes: cap<0>: part=sum_p uhat -> red -> s1; vprep<1>: vT=v1;
// cap<1>: part=sum softmax(uhat.v1)*uhat -> red -> s2; vprep<2>: vT=v1+v2;
// cap<2> -> red -> s3; k_out: squash(s3).

#define Bn 256
#define Pn 2048
#define Cn 10
#define On 16
#define In 8
#define ROW 160
#define PPW 8                  // p per wave
#define NPT (Pn / PPW)         // 256 p-tiles
#define TPB 256
#define GRID (16 * NPT / 4)    // 1024 blocks x 4 independent waves = 4096

typedef _Float16 f16x8 __attribute__((ext_vector_type(8)));
typedef _Float16 h2f __attribute__((ext_vector_type(2)));
typedef float f32x4 __attribute__((ext_vector_type(4)));

__device__ __forceinline__ h2f pack2(float a, float b) {
  __half2 t = __floats2half2_rn(a, b);
  return *reinterpret_cast<h2f*>(&t);
}

// ---- one-time W cast (layout unchanged: [p][c][o][i]) ----
__global__ __launch_bounds__(256) void k_prepw(const float* __restrict__ W,
                                               _Float16* __restrict__ Wh) {
  const size_t base = (size_t)blockIdx.x * 1280;
#pragma unroll
  for (int r = 0; r < 5; ++r) {
    const int i = threadIdx.x + 256 * r;
    Wh[base + i] = (_Float16)W[base + i];
  }
}

// ---- one-time u transpose+cast: block = p-pair, thread = b (exact-line) ----
__global__ __launch_bounds__(256) void k_prepu(const float* __restrict__ u,
                                               _Float16* __restrict__ uT) {
  const int p2 = blockIdx.x * 2;
  const int b = threadIdx.x;
  const float4* src = reinterpret_cast<const float4*>(u + ((size_t)b * Pn + p2) * In);
  const float4 q0 = src[0], q1 = src[1], q2 = src[2], q3 = src[3];
  f16x8 o0, o1;
  o0[0] = (_Float16)q0.x; o0[1] = (_Float16)q0.y; o0[2] = (_Float16)q0.z; o0[3] = (_Float16)q0.w;
  o0[4] = (_Float16)q1.x; o0[5] = (_Float16)q1.y; o0[6] = (_Float16)q1.z; o0[7] = (_Float16)q1.w;
  o1[0] = (_Float16)q2.x; o1[1] = (_Float16)q2.y; o1[2] = (_Float16)q2.z; o1[3] = (_Float16)q2.w;
  o1[4] = (_Float16)q3.x; o1[5] = (_Float16)q3.y; o1[6] = (_Float16)q3.z; o1[7] = (_Float16)q3.w;
  *reinterpret_cast<f16x8*>(uT + ((size_t)p2 * Bn + b) * In) = o0;
  *reinterpret_cast<f16x8*>(uT + ((size_t)(p2 + 1) * Bn + b) * In) = o1;
}

// ---- v prep: thread = (b,c). M=1: v = 0.1-squash(s1). M=2: v12 =
// squash(.1 s1) + squash(s2). Packs into vT[b][quad][c][4] fp16 (80B per
// (b,quad) -> k_cap reads 5 contiguous 16B loads).
template <int M>
__global__ __launch_bounds__(256) void k_vprep(const float* __restrict__ sA,
                                               const float* __restrict__ sB,
                                               _Float16* __restrict__ vT) {
  const int g = blockIdx.x * 256 + threadIdx.x; // [0, 2560) = Bn*Cn
  const int b = g / 10, c = g - 10 * b;
  const float4* pa = reinterpret_cast<const float4*>(sA + (size_t)b * ROW + c * 16);
  const float4 a0 = pa[0], a1 = pa[1], a2 = pa[2], a3 = pa[3];
  float sqA = a0.x * a0.x + a0.y * a0.y + a0.z * a0.z + a0.w * a0.w;
  sqA += a1.x * a1.x + a1.y * a1.y + a1.z * a1.z + a1.w * a1.w;
  sqA += a2.x * a2.x + a2.y * a2.y + a2.z * a2.z + a2.w * a2.w;
  sqA += a3.x * a3.x + a3.y * a3.y + a3.z * a3.z + a3.w * a3.w;
  sqA *= 0.01f;
  const float facA = 0.1f * (sqA / (1.f + sqA)) / sqrtf(sqA + 1e-9f);
  float v[16] = {facA * a0.x, facA * a0.y, facA * a0.z, facA * a0.w,
                 facA * a1.x, facA * a1.y, facA * a1.z, facA * a1.w,
                 facA * a2.x, facA * a2.y, facA * a2.z, facA * a2.w,
                 facA * a3.x, facA * a3.y, facA * a3.z, facA * a3.w};
  if (M == 2) {
    const float4* pb = reinterpret_cast<const float4*>(sB + (size_t)b * ROW + c * 16);
    const float4 b0 = pb[0], b1 = pb[1], b2 = pb[2], b3 = pb[3];
    float sqB = b0.x * b0.x + b0.y * b0.y + b0.z * b0.z + b0.w * b0.w;
    sqB += b1.x * b1.x + b1.y * b1.y + b1.z * b1.z + b1.w * b1.w;
    sqB += b2.x * b2.x + b2.y * b2.y + b2.z * b2.z + b2.w * b2.w;
    sqB += b3.x * b3.x + b3.y * b3.y + b3.z * b3.z + b3.w * b3.w;
    const float facB = (sqB / (1.f + sqB)) / sqrtf(sqB + 1e-9f);
    v[0] += facB * b0.x; v[1] += facB * b0.y; v[2] += facB * b0.z; v[3] += facB * b0.w;
    v[4] += facB * b1.x; v[5] += facB * b1.y; v[6] += facB * b1.z; v[7] += facB * b1.w;
    v[8] += facB * b2.x; v[9] += facB * b2.y; v[10] += facB * b2.z; v[11] += facB * b2.w;
    v[12] += facB * b3.x; v[13] += facB * b3.y; v[14] += facB * b3.z; v[15] += facB * b3.w;
  }
#pragma unroll
  for (int q = 0; q < 4; ++q) {
    union { h2f h[2]; uint2 u2; } o;
    o.h[0] = pack2(v[q * 4 + 0], v[q * 4 + 1]);
    o.h[1] = pack2(v[q * 4 + 2], v[q * 4 + 3]);
    *reinterpret_cast<uint2*>(vT + (size_t)((b * 4 + q) * 10 + c) * 4) = o.u2;
  }
}

template <int MODE>
__global__ __launch_bounds__(TPB) void k_cap(const _Float16* __restrict__ uT,
                                             const _Float16* __restrict__ Wh,
                                             const _Float16* __restrict__ vT,
                                             float* __restrict__ part) {
  // NO LDS, NO barriers: 4 fully independent waves per block.
  const int x = blockIdx.x;
  const int tid = threadIdx.x;
  const int w = tid >> 6;
  const int lane = tid & 63;
  const int gw = x * 4 + w;    // [0, 4096)
  const int btile = gw >> 8;   // 16 b-tiles
  const int ptile = gw & 255;  // 256 p-tiles (block's 4 waves: adjacent pt)
  const int col = lane & 15;   // b within tile; also A's o-row
  const int quad = lane >> 4;  // o-quad in C/D; k-group (only quad0 real)
  const int b = btile * 16 + col;
  const int p0 = ptile * PPW;

  // ---- v slice: 5 contiguous 16B loads (precomputed by k_vprep) ----
  h2f vh[Cn][2];
  if (MODE >= 1) {
    const f16x8* vsrc =
        reinterpret_cast<const f16x8*>(vT + (size_t)(b * 4 + quad) * 40);
    union { f16x8 v8[5]; h2f h[20]; } vu;
#pragma unroll
    for (int r = 0; r < 5; ++r) vu.v8[r] = vsrc[r];
#pragma unroll
    for (int c = 0; c < Cn; ++c) {
      vh[c][0] = vu.h[2 * c];
      vh[c][1] = vu.h[2 * c + 1];
    }
  }

  f32x4 acc[Cn];
  const f32x4 zc = {0.f, 0.f, 0.f, 0.f};
#pragma unroll
  for (int c = 0; c < Cn; ++c) acc[c] = zc;

  const f16x8 zb = {0, 0, 0, 0, 0, 0, 0, 0};
  const bool isq0 = (quad == 0);

#pragma unroll 2
  for (int ip = 0; ip < PPW; ++ip) {
    const int p = p0 + ip;
    const _Float16* wp = Wh + (size_t)p * 1280 + col * 8; // global, L2-hot
    const f16x8 uf =
        *reinterpret_cast<const f16x8*>(uT + ((size_t)p * Bn + b) * In);
    const f16x8 ub = isq0 ? uf : zb; // quads 1-3: K-pad zeros

    if (MODE == 0) {
#pragma unroll
      for (int c = 0; c < Cn; ++c) {
        const f16x8 aW = *reinterpret_cast<const f16x8*>(wp + c * 128);
        acc[c] = __builtin_amdgcn_mfma_f32_16x16x32_f16(aW, ub, acc[c], 0, 0, 0);
      }
    } else {
      float lf[Cn];
      h2f uhh[Cn][2];
#pragma unroll
      for (int c = 0; c < Cn; ++c) {
        const f16x8 aW = *reinterpret_cast<const f16x8*>(wp + c * 128);
        const f32x4 d =
            __builtin_amdgcn_mfma_f32_16x16x32_f16(aW, ub, zc, 0, 0, 0);
        float lp = d[0] * (float)vh[c][0][0];
        lp = __builtin_fmaf(d[1], (float)vh[c][0][1], lp);
        lp = __builtin_fmaf(d[2], (float)vh[c][1][0], lp);
        lp = __builtin_fmaf(d[3], (float)vh[c][1][1], lp);
        lf[c] = lp;
        uhh[c][0] = pack2(d[0], d[1]); // packed: 20 regs not 40
        uhh[c][1] = pack2(d[2], d[3]);
      }
      // reduce over 4 o-quads: 2 shuffles per c (b stays in-lane)
#pragma unroll
      for (int c = 0; c < Cn; ++c) {
        lf[c] += __shfl_xor(lf[c], 16, 64);
        lf[c] += __shfl_xor(lf[c], 32, 64);
      }
      // softmax over 10 in-lane
      float m = fmaxf(fmaxf(lf[0], lf[1]), fmaxf(lf[2], lf[3]));
      m = fmaxf(m, fmaxf(fmaxf(lf[4], lf[5]), fmaxf(lf[6], lf[7])));
      m = fmaxf(m, fmaxf(lf[8], lf[9]));
      float ss = 0.f;
#pragma unroll
      for (int c = 0; c < Cn; ++c) {
        lf[c] = __expf(lf[c] - m);
        ss += lf[c];
      }
      const float inv = 1.f / ss;
#pragma unroll
      for (int c = 0; c < Cn; ++c) {
        const float cv = lf[c] * inv;
        acc[c][0] = __builtin_fmaf(cv, (float)uhh[c][0][0], acc[c][0]);
        acc[c][1] = __builtin_fmaf(cv, (float)uhh[c][0][1], acc[c][1]);
        acc[c][2] = __builtin_fmaf(cv, (float)uhh[c][1][0], acc[c][2]);
        acc[c][3] = __builtin_fmaf(cv, (float)uhh[c][1][1], acc[c][3]);
      }
    }
  }

  // ---- partial store: owner-unique, coalesced, NO atomics ----
  float* pb = part + ((size_t)ptile * Bn + b) * ROW;
#pragma unroll
  for (int c = 0; c < Cn; ++c)
    *reinterpret_cast<f32x4*>(pb + c * 16 + quad * 4) = acc[c];
}

// ---- sum partials -> s. grid (160,8): chunk = 32 p-tiles, atomicAdd (s
// memset once, 8 contenders/cell). Coalesced reads per wave.
__global__ __launch_bounds__(256) void k_red(const float* __restrict__ part,
                                             float* __restrict__ s) {
  const int cell = blockIdx.x * 256 + threadIdx.x; // [0, 40960)
  const int chunk = blockIdx.y;                    // 0..7
  const int b = cell / 160, rem = cell - 160 * b;
  const float* p0 =
      part + ((size_t)(chunk * 32) * Bn + b) * ROW + rem;
  const size_t step = (size_t)Bn * ROW;
  float a0 = 0.f, a1 = 0.f, a2 = 0.f, a3 = 0.f;
  float a4 = 0.f, a5 = 0.f, a6 = 0.f, a7 = 0.f;
#pragma unroll
  for (int pt = 0; pt < 32; pt += 8) { // 8 independent load chains
    a0 += p0[(pt + 0) * step];
    a1 += p0[(pt + 1) * step];
    a2 += p0[(pt + 2) * step];
    a3 += p0[(pt + 3) * step];
    a4 += p0[(pt + 4) * step];
    a5 += p0[(pt + 5) * step];
    a6 += p0[(pt + 6) * step];
    a7 += p0[(pt + 7) * step];
  }
  atomicAdd(&s[cell], ((a0 + a1) + (a2 + a3)) + ((a4 + a5) + (a6 + a7)));
}

__global__ __launch_bounds__(256) void k_out(const float* __restrict__ s,
                                             float* __restrict__ out) {
  const int gi = blockIdx.x * 256 + threadIdx.x; // [0, 2560) = (b,c)
  const int b = gi / 10, c = gi - 10 * b;
  const float* sp = s + (size_t)b * ROW + c * 16;
  float sq = 0.f;
#pragma unroll
  for (int o = 0; o < On; ++o) { const float xx = sp[o]; sq += xx * xx; }
  const float fac = (sq / (1.f + sq)) / sqrtf(sq + 1e-9f);
  float* op = out + (size_t)b * ROW + c * 16;
#pragma unroll
  for (int o = 0; o < On; ++o) op[o] = fac * sp[o];
}

extern "C" void kernel_launch(void* const* d_in, const int* in_sizes, int n_in,
                              void* d_out, int out_size, void* d_ws, size_t ws_size,
                              hipStream_t stream) {
  (void)in_sizes; (void)n_in; (void)out_size;
  const float* u = (const float*)d_in[0];
  const float* W = (const float*)d_in[1];
  float* out = (float*)d_out;
  float* s1 = (float*)d_ws;                    // 3 x [256][160] fp32
  float* s2 = s1 + (size_t)Bn * ROW;
  float* s3 = s2 + (size_t)Bn * ROW;
  float* part = s3 + (size_t)Bn * ROW;         // [256pt][256b][160] fp32, 42MB
  _Float16* Wh = (_Float16*)(part + (size_t)NPT * Bn * ROW); // 5.25MB
  _Float16* uTp = Wh + (size_t)Pn * Cn * On * In;            // 8.4MB
  _Float16* vT = uTp + (size_t)Pn * Bn * In;                 // 80KB
  const size_t need =
      ((size_t)3 * Bn * ROW + (size_t)NPT * Bn * ROW) * sizeof(float) +
      ((size_t)Pn * Cn * On * In + (size_t)Pn * Bn * In + (size_t)Bn * 4 * 40) *
          sizeof(_Float16);
  if (ws_size < need) return;
  hipMemsetAsync(s1, 0, (size_t)3 * Bn * ROW * sizeof(float), stream);
  k_prepw<<<Pn, 256, 0, stream>>>(W, Wh);
  k_prepu<<<Pn / 2, 256, 0, stream>>>(u, uTp);
  k_cap<0><<<GRID, TPB, 0, stream>>>(uTp, Wh, vT, part);
  k_red<<<dim3(160, 8), 256, 0, stream>>>(part, s1);
  k_vprep<1><<<10, 256, 0, stream>>>(s1, s1, vT);
  k_cap<1><<<GRID, TPB, 0, stream>>>(uTp, Wh, vT, part);
  k_red<<<dim3(160, 8), 256, 0, stream>>>(part, s2);
  k_vprep<2><<<10, 256, 0, stream>>>(s1, s2, vT);
  k_cap<2><<<GRID, TPB, 0, stream>>>(uTp, Wh, vT, part);
  k_red<<<dim3(160, 8), 256, 0, stream>>>(part, s3);
  k_out<<<10, 256, 0, stream>>>(s3, out);
}